// Round 3
// baseline (487.702 us; speedup 1.0000x reference)
//
#include <hip/hip_runtime.h>
#include <stdint.h>

#define SEQ   4096
#define NROWS 32768
#define NC    32
#define TC    128

typedef __attribute__((ext_vector_type(8))) __bf16 bf16x8;
typedef __attribute__((ext_vector_type(4))) float  f32x4;
typedef __attribute__((ext_vector_type(8))) unsigned short us8;
typedef __attribute__((ext_vector_type(4))) unsigned short us4;

__device__ __forceinline__ float bf2f(unsigned short u){
  union { unsigned int i; float f; } c; c.i = ((unsigned int)u) << 16; return c.f;
}
__device__ __forceinline__ unsigned short f2bf(float f){
  union { float f; unsigned int i; } c; c.f = f;
  unsigned int x = c.i;
  x += 0x7fffu + ((x >> 16) & 1u);
  return (unsigned short)(x >> 16);
}
__device__ __forceinline__ float wred(float v){
  #pragma unroll
  for (int m = 32; m > 0; m >>= 1) v += __shfl_xor(v, m, 64);
  return v;
}
__device__ __forceinline__ float softplusf(float x){
  return x > 20.f ? x : log1pf(__expf(x));
}
__device__ __forceinline__ void gload_lds16(const unsigned short* g, unsigned short* l){
  __builtin_amdgcn_global_load_lds((const __attribute__((address_space(1))) void*)g,
                                   (__attribute__((address_space(3))) void*)l, 16, 0, 0);
}

// ---------------- prep: transpose/convert weights, combine dt path ----------------
__global__ __launch_bounds__(256) void prep_kernel(
    const float* __restrict__ in_proj_w, const float* __restrict__ x_proj_w,
    const float* __restrict__ dt_proj_w, const float* __restrict__ out_proj_w,
    const float* __restrict__ proj_w,    const float* __restrict__ A_log,
    unsigned short* __restrict__ wInT, unsigned short* __restrict__ w2T,
    unsigned short* __restrict__ woutT, unsigned short* __restrict__ wprojT,
    float* __restrict__ Aneg)
{
  int i = blockIdx.x * 256 + threadIdx.x;
  if (i < 262144) {                      // in_proj^T : [1024][256]
    int n = i >> 8, k = i & 255;
    wInT[i] = f2bf(in_proj_w[k * 1024 + n]);
    return;
  }
  i -= 262144;
  if (i < 327680) {                      // W2^T : [640][512]  (dt_full | B | C | pad)
    int n = i >> 9, k = i & 511;
    float v = 0.f;
    if (n < 512) {
      #pragma unroll
      for (int r = 0; r < 16; ++r) v += x_proj_w[k * 48 + r] * dt_proj_w[r * 512 + n];
    } else if (n < 544) {
      v = x_proj_w[k * 48 + 16 + (n - 512)];
    }
    w2T[i] = f2bf(v);
    return;
  }
  i -= 327680;
  if (i < 131072) {                      // out_proj^T : [256][512]
    int n = i >> 9, k = i & 511;
    woutT[i] = f2bf(out_proj_w[k * 256 + n]);
    return;
  }
  i -= 131072;
  if (i < 131072) {                      // proj^T : [256][512]
    int n = i >> 9, k = i & 511;
    wprojT[i] = f2bf(proj_w[k * 256 + n]);
    return;
  }
  i -= 131072;
  if (i < 8192) Aneg[i] = -__expf(A_log[i]);   // A = -exp(A_log)
}

// ---------------- fused: pos-encode + LN + silu + rmsnorm (4 rows/block) ----------------
__global__ __launch_bounds__(256) void pre_kernel(
    const float* __restrict__ x, const float* __restrict__ pos_w, const float* __restrict__ pos_b,
    const float* __restrict__ lnw, const float* __restrict__ lnb, const float* __restrict__ rmsw,
    unsigned short* __restrict__ u, unsigned short* __restrict__ xsilu)
{
  int r = blockIdx.x * 4 + (threadIdx.x >> 6);
  int lane = threadIdx.x & 63;
  int t = r & (SEQ - 1);
  float ft = (float)t;
  float denom = (float)(SEQ / 12 + 1);
  float c0  = ft / (float)SEQ;
  float c12 = floorf(ft / 12.f) / denom;
  float c34 = fmodf(ft, 12.f) / 12.f;
  float c56 = floorf((ft + 6.f) / 12.f) / denom;
  float c78 = fmodf(ft + 6.f, 12.f) / 12.f;
  float coords[9] = {c0, c12, c12, c34, c34, c56, c56, c78, c78};

  float4 xv = *(const float4*)(x + (size_t)r * 256 + lane * 4);
  float xin[4] = {xv.x, xv.y, xv.z, xv.w};
  float pe[4];
  #pragma unroll
  for (int j = 0; j < 4; ++j) {
    int col = lane * 4 + j;
    float p = pos_b[col];
    #pragma unroll
    for (int k = 0; k < 9; ++k) p += coords[k] * pos_w[k * 256 + col];
    pe[j] = xin[j] + p;
  }
  float s1 = pe[0] + pe[1] + pe[2] + pe[3];
  float s2 = pe[0]*pe[0] + pe[1]*pe[1] + pe[2]*pe[2] + pe[3]*pe[3];
  s1 = wred(s1); s2 = wred(s2);
  float mean = s1 * (1.f / 256.f);
  float var  = s2 * (1.f / 256.f) - mean * mean;
  float rstd = rsqrtf(var + 1e-5f);
  float xl[4]; float q = 0.f;
  #pragma unroll
  for (int j = 0; j < 4; ++j) {
    int col = lane * 4 + j;
    xl[j] = (pe[j] - mean) * rstd * lnw[col] + lnb[col];
    q += xl[j] * xl[j];
  }
  q = wred(q);
  float rrms = rsqrtf(q * (1.f / 256.f) + 1e-5f);
  #pragma unroll
  for (int j = 0; j < 4; ++j) {
    int col = lane * 4 + j;
    u[(size_t)r * 256 + col] = f2bf(xl[j] * rrms * rmsw[col]);
    float v = xl[j];
    xsilu[(size_t)r * 256 + col] = f2bf(v / (1.f + __expf(-v)));
  }
}

// ---------------- depthwise conv(4) + silu ----------------
__global__ __launch_bounds__(256) void conv_kernel(
    const unsigned short* __restrict__ xm, const float* __restrict__ cw,
    const float* __restrict__ cb, unsigned short* __restrict__ xc)
{
  int tid = blockIdx.x * 256 + threadIdx.x;      // 8*4096*64
  int d8 = (tid & 63) * 8;
  int t  = (tid >> 6) & (SEQ - 1);
  int b  = tid >> 18;
  float acc[8];
  #pragma unroll
  for (int j = 0; j < 8; ++j) acc[j] = cb[d8 + j];
  #pragma unroll
  for (int k = 0; k < 4; ++k) {
    int ts = t - 3 + k;
    if (ts >= 0) {
      us8 v = *(const us8*)(xm + ((size_t)b * SEQ + ts) * 512 + d8);
      #pragma unroll
      for (int j = 0; j < 8; ++j) acc[j] += bf2f(v[j]) * cw[k * 512 + d8 + j];
    }
  }
  us8 o;
  #pragma unroll
  for (int j = 0; j < 8; ++j) {
    float s = acc[j] / (1.f + __expf(-acc[j]));
    o[j] = f2bf(s);
  }
  *(us8*)(xc + ((size_t)b * SEQ + t) * 512 + d8) = o;
}

// ---------------- bf16 MFMA GEMM body: C = A @ Bt^T, 128x128 tile ----------------
// 2-phase double-buffered (T3-minimum), BK=32, XOR-swizzled LDS (T2 via
// pre-swizzled global source per rule #21; ds_read applies the same XOR).
// MODE 0: split store xm|z  MODE 1: softplus->dt | BC  MODE 2: bf16 store  MODE 3: fp32 +bias +x
template<int MODE>
__device__ __forceinline__ void gemm_body(
    const unsigned short* __restrict__ A0, const unsigned short* __restrict__ A1,
    const unsigned short* __restrict__ Bt,
    int K, int Asplit, int Astride,
    unsigned short* __restrict__ O0, unsigned short* __restrict__ O1,
    const float* __restrict__ e0, const float* __restrict__ e1,
    float* __restrict__ fout)
{
  __shared__ unsigned short As[2][128 * 32];
  __shared__ unsigned short Bs[2][128 * 32];
  const int tid  = threadIdx.x;
  const int wave = tid >> 6, lane = tid & 63;
  const int brow = blockIdx.y * 128, bcol = blockIdx.x * 128;
  const int wr = wave >> 1, wc = wave & 1;
  const int lrow = lane & 15, ksub = lane >> 4;       // read decomposition
  const int srow = lane >> 2, ssub = lane & 3;        // stage decomposition
  const int swzS  = ((ssub ^ (srow & 3)) << 3);       // staged col-block (ushorts)
  const int rdswz = ((ksub ^ (lrow & 3)) << 3);       // read col-block (ushorts)

  f32x4 acc[4][4];
  #pragma unroll
  for (int m = 0; m < 4; ++m)
    #pragma unroll
    for (int n = 0; n < 4; ++n) acc[m][n] = f32x4{0.f, 0.f, 0.f, 0.f};

  const int nsteps = K >> 5;

  auto stage = [&](int buf, int k0) {
    const unsigned short* Ab; int kk;
    if (k0 < Asplit) { Ab = A0; kk = k0; } else { Ab = A1; kk = k0 - Asplit; }
    #pragma unroll
    for (int i = 0; i < 2; ++i) {
      int c = wave * 2 + i;             // chunk 0..7 (16 rows each)
      int r = c * 16 + srow;
      gload_lds16(Ab + (size_t)(brow + r) * Astride + kk + swzS, &As[buf][c * 512]);
      gload_lds16(Bt + (size_t)(bcol + r) * K + k0 + swzS,       &Bs[buf][c * 512]);
    }
  };

  stage(0, 0);
  __syncthreads();
  int buf = 0;
  for (int step = 0; step < nsteps; ++step) {
    if (step + 1 < nsteps) stage(buf ^ 1, (step + 1) << 5);   // prefetch first
    bf16x8 av[4], bv[4];
    #pragma unroll
    for (int m = 0; m < 4; ++m)
      av[m] = *(const bf16x8*)(&As[buf][(wr * 64 + m * 16 + lrow) * 32 + rdswz]);
    #pragma unroll
    for (int n = 0; n < 4; ++n)
      bv[n] = *(const bf16x8*)(&Bs[buf][(wc * 64 + n * 16 + lrow) * 32 + rdswz]);
    #pragma unroll
    for (int m = 0; m < 4; ++m)
      #pragma unroll
      for (int n = 0; n < 4; ++n)
        acc[m][n] = __builtin_amdgcn_mfma_f32_16x16x32_bf16(av[m], bv[n], acc[m][n], 0, 0, 0);
    __syncthreads();                    // one barrier per K-step
    buf ^= 1;
  }

  const int r0 = brow + wr * 64 + (lane >> 4) * 4;
  const int c0 = bcol + wc * 64 + lrow;
  #pragma unroll
  for (int m = 0; m < 4; ++m) {
    #pragma unroll
    for (int n = 0; n < 4; ++n) {
      int col = c0 + n * 16;
      #pragma unroll
      for (int rr = 0; rr < 4; ++rr) {
        int row = r0 + m * 16 + rr;
        float v = acc[m][n][rr];
        if (MODE == 0) {
          if (col < 512) O0[(size_t)row * 512 + col] = f2bf(v);
          else           O1[(size_t)row * 512 + col - 512] = f2bf(v);
        } else if (MODE == 1) {
          if (col < 512) {
            O0[(size_t)row * 512 + col] = f2bf(softplusf(v + e0[col]));
          } else if (col < 544) {
            O1[(size_t)row * 32 + (col - 512)] = f2bf(v);
          }
        } else if (MODE == 2) {
          O0[(size_t)row * 256 + col] = f2bf(v);
        } else {
          fout[(size_t)row * 256 + col] = v + e0[col] + e1[(size_t)row * 256 + col];
        }
      }
    }
  }
}

// distinctly-named wrappers for rocprof attribution
__global__ __launch_bounds__(256) void gemm_inproj(
    const unsigned short* A0, const unsigned short* Bt, int K, int Astride,
    unsigned short* O0, unsigned short* O1)
{ gemm_body<0>(A0, nullptr, Bt, K, 1 << 30, Astride, O0, O1, nullptr, nullptr, nullptr); }

__global__ __launch_bounds__(256) void gemm_dtbc(
    const unsigned short* A0, const unsigned short* Bt, int K, int Astride,
    unsigned short* O0, unsigned short* O1, const float* e0)
{ gemm_body<1>(A0, nullptr, Bt, K, 1 << 30, Astride, O0, O1, e0, nullptr, nullptr); }

__global__ __launch_bounds__(256) void gemm_outproj(
    const unsigned short* A0, const unsigned short* Bt, int K, int Astride,
    unsigned short* O0)
{ gemm_body<2>(A0, nullptr, Bt, K, 1 << 30, Astride, O0, nullptr, nullptr, nullptr, nullptr); }

__global__ __launch_bounds__(256) void gemm_final(
    const unsigned short* A0, const unsigned short* A1, const unsigned short* Bt,
    int K, int Asplit, int Astride,
    const float* e0, const float* e1, float* fout)
{ gemm_body<3>(A0, A1, Bt, K, Asplit, Astride, nullptr, nullptr, e0, e1, fout); }

// ---------------- chunked selective scan ----------------
__global__ __launch_bounds__(256) void scan_pass1(
    const unsigned short* __restrict__ dt, const unsigned short* __restrict__ xc,
    const unsigned short* __restrict__ BC, const float* __restrict__ Aneg,
    float* __restrict__ PS)
{
  int tid = blockIdx.x * 256 + threadIdx.x;       // c*4096 + bd
  int bd = tid & 4095, c = tid >> 12;
  int b = bd >> 9, d = bd & 511;
  float a[16], h[16];
  #pragma unroll
  for (int s = 0; s < 16; ++s) { a[s] = Aneg[d * 16 + s]; h[s] = 0.f; }
  size_t rbase = (size_t)b * SEQ + (size_t)c * TC;
  float sdt = 0.f;
  unsigned short dnx = dt[rbase * 512 + d], xnx = xc[rbase * 512 + d];
  const us8* pb = (const us8*)(BC + rbase * 32);
  us8 B0n = pb[0], B1n = pb[1];
  for (int t = 0; t < TC; ++t) {
    float dtv = bf2f(dnx), xv = bf2f(xnx);
    us8 b0 = B0n, b1 = B1n;
    if (t + 1 < TC) {
      size_t r = rbase + t + 1;
      dnx = dt[r * 512 + d]; xnx = xc[r * 512 + d];
      const us8* p2 = (const us8*)(BC + r * 32);
      B0n = p2[0]; B1n = p2[1];
    }
    sdt += dtv;
    float cb = dtv * xv;
    #pragma unroll
    for (int s = 0; s < 16; ++s) {
      float e  = __expf(dtv * a[s]);
      float bb = bf2f(s < 8 ? (unsigned short)b0[s] : (unsigned short)b1[s - 8]);
      h[s] = e * h[s] + cb * bb;
    }
  }
  float* o = PS + (size_t)tid * 32;
  #pragma unroll
  for (int s = 0; s < 16; ++s) { o[s] = __expf(sdt * a[s]); o[16 + s] = h[s]; }
}

__global__ __launch_bounds__(256) void scan_combine(
    const float* __restrict__ PS, float* __restrict__ H0)
{
  int tid = blockIdx.x * 256 + threadIdx.x;       // bd*16 + s
  int bd = tid >> 4, s = tid & 15;
  float h = 0.f;
  for (int c = 0; c < NC; ++c) {
    size_t idx = (size_t)c * 4096 + bd;
    H0[idx * 16 + s] = h;
    h = PS[idx * 32 + s] * h + PS[idx * 32 + 16 + s];
  }
}

__global__ __launch_bounds__(256) void scan_pass3(
    const unsigned short* __restrict__ dt, const unsigned short* __restrict__ xc,
    const unsigned short* __restrict__ BC, const unsigned short* __restrict__ z,
    const float* __restrict__ Aneg, const float* __restrict__ Dp,
    const float* __restrict__ H0, unsigned short* __restrict__ yg)
{
  int tid = blockIdx.x * 256 + threadIdx.x;
  int bd = tid & 4095, c = tid >> 12;
  int b = bd >> 9, d = bd & 511;
  float a[16], h[16];
  #pragma unroll
  for (int s = 0; s < 16; ++s) {
    a[s] = Aneg[d * 16 + s];
    h[s] = H0[(size_t)tid * 16 + s];
  }
  float dpar = Dp[d];
  size_t rbase = (size_t)b * SEQ + (size_t)c * TC;
  unsigned short dnx = dt[rbase * 512 + d], xnx = xc[rbase * 512 + d], znx = z[rbase * 512 + d];
  const us8* pb = (const us8*)(BC + rbase * 32);
  us8 B0n = pb[0], B1n = pb[1], C0n = pb[2], C1n = pb[3];
  for (int t = 0; t < TC; ++t) {
    float dtv = bf2f(dnx), xv = bf2f(xnx), zv = bf2f(znx);
    us8 b0 = B0n, b1 = B1n, cc0 = C0n, cc1 = C1n;
    if (t + 1 < TC) {
      size_t r = rbase + t + 1;
      dnx = dt[r * 512 + d]; xnx = xc[r * 512 + d]; znx = z[r * 512 + d];
      const us8* p2 = (const us8*)(BC + r * 32);
      B0n = p2[0]; B1n = p2[1]; C0n = p2[2]; C1n = p2[3];
    }
    float cb = dtv * xv, y = 0.f;
    #pragma unroll
    for (int s = 0; s < 16; ++s) {
      float e  = __expf(dtv * a[s]);
      float bb = bf2f(s < 8 ? (unsigned short)b0[s] : (unsigned short)b1[s - 8]);
      float cv = bf2f(s < 8 ? (unsigned short)cc0[s] : (unsigned short)cc1[s - 8]);
      h[s] = e * h[s] + cb * bb;
      y += h[s] * cv;
    }
    float yo = y + dpar * xv;
    float sz = zv / (1.f + __expf(-zv));
    yg[(rbase + t) * 512 + d] = f2bf(yo * sz);
  }
}

// ---------------- LN of m_out -> m_norm (bf16), 4 rows/block ----------------
__global__ __launch_bounds__(256) void ln_kernel(
    const unsigned short* __restrict__ mo, const float* __restrict__ w,
    const float* __restrict__ bb, unsigned short* __restrict__ mn)
{
  int r = blockIdx.x * 4 + (threadIdx.x >> 6);
  int lane = threadIdx.x & 63;
  us4 mv = *(const us4*)(mo + (size_t)r * 256 + lane * 4);
  float v[4];
  #pragma unroll
  for (int j = 0; j < 4; ++j) v[j] = bf2f(mv[j]);
  float s1 = v[0] + v[1] + v[2] + v[3];
  float s2 = v[0]*v[0] + v[1]*v[1] + v[2]*v[2] + v[3]*v[3];
  s1 = wred(s1); s2 = wred(s2);
  float mean = s1 * (1.f / 256.f);
  float var  = s2 * (1.f / 256.f) - mean * mean;
  float rstd = rsqrtf(var + 1e-5f);
  #pragma unroll
  for (int j = 0; j < 4; ++j) {
    int col = lane * 4 + j;
    mn[(size_t)r * 256 + col] = f2bf((v[j] - mean) * rstd * w[col] + bb[col]);
  }
}

extern "C" void kernel_launch(void* const* d_in, const int* in_sizes, int n_in,
                              void* d_out, int out_size, void* d_ws, size_t ws_size,
                              hipStream_t stream) {
  (void)in_sizes; (void)n_in; (void)out_size; (void)ws_size;
  const float* x         = (const float*)d_in[0];
  const float* pos_w     = (const float*)d_in[1];
  const float* pos_b     = (const float*)d_in[2];
  const float* ln_in_w   = (const float*)d_in[3];
  const float* ln_in_b   = (const float*)d_in[4];
  const float* rms_w     = (const float*)d_in[5];
  const float* in_proj_w = (const float*)d_in[6];
  const float* conv_w    = (const float*)d_in[7];
  const float* conv_b    = (const float*)d_in[8];
  const float* x_proj_w  = (const float*)d_in[9];
  const float* dt_proj_w = (const float*)d_in[10];
  const float* dt_proj_b = (const float*)d_in[11];
  const float* A_log     = (const float*)d_in[12];
  const float* D_param   = (const float*)d_in[13];
  const float* out_proj_w= (const float*)d_in[14];
  const float* ln_fwd_w  = (const float*)d_in[15];
  const float* ln_fwd_b  = (const float*)d_in[16];
  const float* proj_w    = (const float*)d_in[17];
  const float* proj_b    = (const float*)d_in[18];
  float* out = (float*)d_out;

  char* w = (char*)d_ws;
  unsigned short* u_buf  = (unsigned short*)(w + 0);
  float*          PS     = (float*)(w + 0);
  unsigned short* mout   = (unsigned short*)(w + 0);
  unsigned short* xsilu  = (unsigned short*)(w + 16777216);
  unsigned short* xm     = (unsigned short*)(w + 33554432);   // then yg
  unsigned short* yg     = xm;
  unsigned short* zb     = (unsigned short*)(w + 67108864);
  unsigned short* xc     = (unsigned short*)(w + 100663296);
  unsigned short* dtb    = (unsigned short*)(w + 134217728);  // then mnorm
  unsigned short* mnorm  = dtb;
  unsigned short* BC     = (unsigned short*)(w + 167772160);
  float*          H0     = (float*)(w + 169869312);
  unsigned short* wInT   = (unsigned short*)(w + 178257920);
  unsigned short* w2T    = (unsigned short*)(w + 178782208);
  unsigned short* woutT  = (unsigned short*)(w + 179437568);
  unsigned short* wprojT = (unsigned short*)(w + 179699712);
  float*          Aneg   = (float*)(w + 179961856);

  prep_kernel<<<3360, 256, 0, stream>>>(in_proj_w, x_proj_w, dt_proj_w, out_proj_w,
                                        proj_w, A_log, wInT, w2T, woutT, wprojT, Aneg);
  pre_kernel<<<8192, 256, 0, stream>>>(x, pos_w, pos_b, ln_in_w, ln_in_b, rms_w, u_buf, xsilu);
  gemm_inproj<<<dim3(8, 256), 256, 0, stream>>>(u_buf, wInT, 256, 256, xm, zb);
  conv_kernel<<<8192, 256, 0, stream>>>(xm, conv_w, conv_b, xc);
  gemm_dtbc<<<dim3(5, 256), 256, 0, stream>>>(xc, w2T, 512, 512, dtb, BC, dt_proj_b);
  scan_pass1<<<512, 256, 0, stream>>>(dtb, xc, BC, Aneg, PS);
  scan_combine<<<256, 256, 0, stream>>>(PS, H0);
  scan_pass3<<<512, 256, 0, stream>>>(dtb, xc, BC, zb, Aneg, D_param, H0, yg);
  gemm_outproj<<<dim3(2, 256), 256, 0, stream>>>(yg, woutT, 512, 512, mout);
  ln_kernel<<<8192, 256, 0, stream>>>(mout, ln_fwd_w, ln_fwd_b, mnorm);
  gemm_final<<<dim3(2, 256), 256, 0, stream>>>(mnorm, xsilu, wprojT, 512, 256, 256,
                                               proj_b, x, out);
}

// Round 4
// 483.531 us; speedup vs baseline: 1.0086x; 1.0086x over previous
//
#include <hip/hip_runtime.h>
#include <stdint.h>

#define SEQ   4096
#define NROWS 32768
#define NC    32
#define TC    128

typedef __attribute__((ext_vector_type(8))) __bf16 bf16x8;
typedef __attribute__((ext_vector_type(4))) float  f32x4;
typedef __attribute__((ext_vector_type(8))) unsigned short us8;
typedef __attribute__((ext_vector_type(4))) unsigned short us4;

__device__ __forceinline__ float bf2f(unsigned short u){
  union { unsigned int i; float f; } c; c.i = ((unsigned int)u) << 16; return c.f;
}
__device__ __forceinline__ unsigned short f2bf(float f){
  union { float f; unsigned int i; } c; c.f = f;
  unsigned int x = c.i;
  x += 0x7fffu + ((x >> 16) & 1u);
  return (unsigned short)(x >> 16);
}
__device__ __forceinline__ float wred(float v){
  #pragma unroll
  for (int m = 32; m > 0; m >>= 1) v += __shfl_xor(v, m, 64);
  return v;
}
__device__ __forceinline__ float softplusf(float x){
  return x > 20.f ? x : log1pf(__expf(x));
}
__device__ __forceinline__ void gload_lds16(const unsigned short* g, unsigned short* l){
  __builtin_amdgcn_global_load_lds((const __attribute__((address_space(1))) void*)g,
                                   (__attribute__((address_space(3))) void*)l, 16, 0, 0);
}

// ---------------- prep: transpose/convert weights, combine dt path ----------------
__global__ __launch_bounds__(256) void prep_kernel(
    const float* __restrict__ in_proj_w, const float* __restrict__ x_proj_w,
    const float* __restrict__ dt_proj_w, const float* __restrict__ out_proj_w,
    const float* __restrict__ proj_w,    const float* __restrict__ A_log,
    unsigned short* __restrict__ wInT, unsigned short* __restrict__ w2T,
    unsigned short* __restrict__ woutT, unsigned short* __restrict__ wprojT,
    float* __restrict__ Aneg)
{
  int i = blockIdx.x * 256 + threadIdx.x;
  if (i < 262144) {                      // in_proj^T : [1024][256]
    int n = i >> 8, k = i & 255;
    wInT[i] = f2bf(in_proj_w[k * 1024 + n]);
    return;
  }
  i -= 262144;
  if (i < 327680) {                      // W2^T : [640][512]  (dt_full | B | C | pad)
    int n = i >> 9, k = i & 511;
    float v = 0.f;
    if (n < 512) {
      #pragma unroll
      for (int r = 0; r < 16; ++r) v += x_proj_w[k * 48 + r] * dt_proj_w[r * 512 + n];
    } else if (n < 544) {
      v = x_proj_w[k * 48 + 16 + (n - 512)];
    }
    w2T[i] = f2bf(v);
    return;
  }
  i -= 327680;
  if (i < 131072) {                      // out_proj^T : [256][512]
    int n = i >> 9, k = i & 511;
    woutT[i] = f2bf(out_proj_w[k * 256 + n]);
    return;
  }
  i -= 131072;
  if (i < 131072) {                      // proj^T : [256][512]
    int n = i >> 9, k = i & 511;
    wprojT[i] = f2bf(proj_w[k * 256 + n]);
    return;
  }
  i -= 131072;
  if (i < 8192) Aneg[i] = -__expf(A_log[i]);   // A = -exp(A_log)
}

// ---------------- fused: pos-encode + LN + silu + rmsnorm (4 rows/block) ----------------
__global__ __launch_bounds__(256) void pre_kernel(
    const float* __restrict__ x, const float* __restrict__ pos_w, const float* __restrict__ pos_b,
    const float* __restrict__ lnw, const float* __restrict__ lnb, const float* __restrict__ rmsw,
    unsigned short* __restrict__ u, unsigned short* __restrict__ xsilu)
{
  int r = blockIdx.x * 4 + (threadIdx.x >> 6);
  int lane = threadIdx.x & 63;
  int t = r & (SEQ - 1);
  float ft = (float)t;
  float denom = (float)(SEQ / 12 + 1);
  float c0  = ft / (float)SEQ;
  float c12 = floorf(ft / 12.f) / denom;
  float c34 = fmodf(ft, 12.f) / 12.f;
  float c56 = floorf((ft + 6.f) / 12.f) / denom;
  float c78 = fmodf(ft + 6.f, 12.f) / 12.f;
  float coords[9] = {c0, c12, c12, c34, c34, c56, c56, c78, c78};

  float4 xv = *(const float4*)(x + (size_t)r * 256 + lane * 4);
  float xin[4] = {xv.x, xv.y, xv.z, xv.w};
  float pe[4];
  #pragma unroll
  for (int j = 0; j < 4; ++j) {
    int col = lane * 4 + j;
    float p = pos_b[col];
    #pragma unroll
    for (int k = 0; k < 9; ++k) p += coords[k] * pos_w[k * 256 + col];
    pe[j] = xin[j] + p;
  }
  float s1 = pe[0] + pe[1] + pe[2] + pe[3];
  float s2 = pe[0]*pe[0] + pe[1]*pe[1] + pe[2]*pe[2] + pe[3]*pe[3];
  s1 = wred(s1); s2 = wred(s2);
  float mean = s1 * (1.f / 256.f);
  float var  = s2 * (1.f / 256.f) - mean * mean;
  float rstd = rsqrtf(var + 1e-5f);
  float xl[4]; float q = 0.f;
  #pragma unroll
  for (int j = 0; j < 4; ++j) {
    int col = lane * 4 + j;
    xl[j] = (pe[j] - mean) * rstd * lnw[col] + lnb[col];
    q += xl[j] * xl[j];
  }
  q = wred(q);
  float rrms = rsqrtf(q * (1.f / 256.f) + 1e-5f);
  #pragma unroll
  for (int j = 0; j < 4; ++j) {
    int col = lane * 4 + j;
    u[(size_t)r * 256 + col] = f2bf(xl[j] * rrms * rmsw[col]);
    float v = xl[j];
    xsilu[(size_t)r * 256 + col] = f2bf(v / (1.f + __expf(-v)));
  }
}

// ---------------- depthwise conv(4) + silu ----------------
__global__ __launch_bounds__(256) void conv_kernel(
    const unsigned short* __restrict__ xm, const float* __restrict__ cw,
    const float* __restrict__ cb, unsigned short* __restrict__ xc)
{
  int tid = blockIdx.x * 256 + threadIdx.x;      // 8*4096*64
  int d8 = (tid & 63) * 8;
  int t  = (tid >> 6) & (SEQ - 1);
  int b  = tid >> 18;
  float acc[8];
  #pragma unroll
  for (int j = 0; j < 8; ++j) acc[j] = cb[d8 + j];
  #pragma unroll
  for (int k = 0; k < 4; ++k) {
    int ts = t - 3 + k;
    if (ts >= 0) {
      us8 v = *(const us8*)(xm + ((size_t)b * SEQ + ts) * 512 + d8);
      #pragma unroll
      for (int j = 0; j < 8; ++j) acc[j] += bf2f(v[j]) * cw[k * 512 + d8 + j];
    }
  }
  us8 o;
  #pragma unroll
  for (int j = 0; j < 8; ++j) {
    float s = acc[j] / (1.f + __expf(-acc[j]));
    o[j] = f2bf(s);
  }
  *(us8*)(xc + ((size_t)b * SEQ + t) * 512 + d8) = o;
}

// ---------------- bf16 MFMA GEMM body: C = A @ Bt^T, 128x128 tile ----------------
// 2-phase double-buffered (T3-minimum), BK=32, XOR-swizzled LDS (T2 via
// pre-swizzled global source per rule #21; ds_read applies the same XOR).
// MODE 0: split store xm|z  MODE 1: softplus->dt | BC  MODE 2: bf16 store  MODE 3: fp32 +bias +x
template<int MODE>
__device__ __forceinline__ void gemm_body(
    const unsigned short* __restrict__ A0, const unsigned short* __restrict__ A1,
    const unsigned short* __restrict__ Bt,
    int K, int Asplit, int Astride,
    unsigned short* __restrict__ O0, unsigned short* __restrict__ O1,
    const float* __restrict__ e0, const float* __restrict__ e1,
    float* __restrict__ fout)
{
  __shared__ unsigned short As[2][128 * 32];
  __shared__ unsigned short Bs[2][128 * 32];
  const int tid  = threadIdx.x;
  const int wave = tid >> 6, lane = tid & 63;
  const int brow = blockIdx.y * 128, bcol = blockIdx.x * 128;
  const int wr = wave >> 1, wc = wave & 1;
  const int lrow = lane & 15, ksub = lane >> 4;       // read decomposition
  const int srow = lane >> 2, ssub = lane & 3;        // stage decomposition
  const int swzS  = ((ssub ^ (srow & 3)) << 3);       // staged col-block (ushorts)
  const int rdswz = ((ksub ^ (lrow & 3)) << 3);       // read col-block (ushorts)

  f32x4 acc[4][4];
  #pragma unroll
  for (int m = 0; m < 4; ++m)
    #pragma unroll
    for (int n = 0; n < 4; ++n) acc[m][n] = f32x4{0.f, 0.f, 0.f, 0.f};

  const int nsteps = K >> 5;

  auto stage = [&](int buf, int k0) {
    const unsigned short* Ab; int kk;
    if (k0 < Asplit) { Ab = A0; kk = k0; } else { Ab = A1; kk = k0 - Asplit; }
    #pragma unroll
    for (int i = 0; i < 2; ++i) {
      int c = wave * 2 + i;             // chunk 0..7 (16 rows each)
      int r = c * 16 + srow;
      gload_lds16(Ab + (size_t)(brow + r) * Astride + kk + swzS, &As[buf][c * 512]);
      gload_lds16(Bt + (size_t)(bcol + r) * K + k0 + swzS,       &Bs[buf][c * 512]);
    }
  };

  stage(0, 0);
  __syncthreads();
  int buf = 0;
  for (int step = 0; step < nsteps; ++step) {
    if (step + 1 < nsteps) stage(buf ^ 1, (step + 1) << 5);   // prefetch first
    bf16x8 av[4], bv[4];
    #pragma unroll
    for (int m = 0; m < 4; ++m)
      av[m] = *(const bf16x8*)(&As[buf][(wr * 64 + m * 16 + lrow) * 32 + rdswz]);
    #pragma unroll
    for (int n = 0; n < 4; ++n)
      bv[n] = *(const bf16x8*)(&Bs[buf][(wc * 64 + n * 16 + lrow) * 32 + rdswz]);
    #pragma unroll
    for (int m = 0; m < 4; ++m)
      #pragma unroll
      for (int n = 0; n < 4; ++n)
        acc[m][n] = __builtin_amdgcn_mfma_f32_16x16x32_bf16(av[m], bv[n], acc[m][n], 0, 0, 0);
    __syncthreads();                    // one barrier per K-step
    buf ^= 1;
  }

  const int r0 = brow + wr * 64 + (lane >> 4) * 4;
  const int c0 = bcol + wc * 64 + lrow;
  #pragma unroll
  for (int m = 0; m < 4; ++m) {
    #pragma unroll
    for (int n = 0; n < 4; ++n) {
      int col = c0 + n * 16;
      #pragma unroll
      for (int rr = 0; rr < 4; ++rr) {
        int row = r0 + m * 16 + rr;
        float v = acc[m][n][rr];
        if (MODE == 0) {
          if (col < 512) O0[(size_t)row * 512 + col] = f2bf(v);
          else           O1[(size_t)row * 512 + col - 512] = f2bf(v);
        } else if (MODE == 1) {
          if (col < 512) {
            O0[(size_t)row * 512 + col] = f2bf(softplusf(v + e0[col]));
          } else if (col < 544) {
            O1[(size_t)row * 32 + (col - 512)] = f2bf(v);
          }
        } else if (MODE == 2) {
          O0[(size_t)row * 256 + col] = f2bf(v);
        } else {
          fout[(size_t)row * 256 + col] = v + e0[col] + e1[(size_t)row * 256 + col];
        }
      }
    }
  }
}

// distinctly-named wrappers for rocprof attribution
__global__ __launch_bounds__(256) void gemm_inproj(
    const unsigned short* A0, const unsigned short* Bt, int K, int Astride,
    unsigned short* O0, unsigned short* O1)
{ gemm_body<0>(A0, nullptr, Bt, K, 1 << 30, Astride, O0, O1, nullptr, nullptr, nullptr); }

__global__ __launch_bounds__(256) void gemm_dtbc(
    const unsigned short* A0, const unsigned short* Bt, int K, int Astride,
    unsigned short* O0, unsigned short* O1, const float* e0)
{ gemm_body<1>(A0, nullptr, Bt, K, 1 << 30, Astride, O0, O1, e0, nullptr, nullptr); }

__global__ __launch_bounds__(256) void gemm_outproj(
    const unsigned short* A0, const unsigned short* Bt, int K, int Astride,
    unsigned short* O0)
{ gemm_body<2>(A0, nullptr, Bt, K, 1 << 30, Astride, O0, nullptr, nullptr, nullptr, nullptr); }

__global__ __launch_bounds__(256) void gemm_final(
    const unsigned short* A0, const unsigned short* A1, const unsigned short* Bt,
    int K, int Asplit, int Astride,
    const float* e0, const float* e1, float* fout)
{ gemm_body<3>(A0, A1, Bt, K, Asplit, Astride, nullptr, nullptr, e0, e1, fout); }

// ---------------- chunked selective scan ----------------
__global__ __launch_bounds__(256) void scan_pass1(
    const unsigned short* __restrict__ dt, const unsigned short* __restrict__ xc,
    const unsigned short* __restrict__ BC, const float* __restrict__ Aneg,
    float* __restrict__ PS)
{
  int tid = blockIdx.x * 256 + threadIdx.x;       // c*4096 + bd
  int bd = tid & 4095, c = tid >> 12;
  int b = bd >> 9, d = bd & 511;
  float a[16], h[16];
  #pragma unroll
  for (int s = 0; s < 16; ++s) { a[s] = Aneg[d * 16 + s]; h[s] = 0.f; }
  size_t rbase = (size_t)b * SEQ + (size_t)c * TC;
  float sdt = 0.f;
  unsigned short dnx = dt[rbase * 512 + d], xnx = xc[rbase * 512 + d];
  const us8* pb = (const us8*)(BC + rbase * 32);
  us8 B0n = pb[0], B1n = pb[1];
  for (int t = 0; t < TC; ++t) {
    float dtv = bf2f(dnx), xv = bf2f(xnx);
    us8 b0 = B0n, b1 = B1n;
    if (t + 1 < TC) {
      size_t r = rbase + t + 1;
      dnx = dt[r * 512 + d]; xnx = xc[r * 512 + d];
      const us8* p2 = (const us8*)(BC + r * 32);
      B0n = p2[0]; B1n = p2[1];
    }
    sdt += dtv;
    float cb = dtv * xv;
    #pragma unroll
    for (int s = 0; s < 16; ++s) {
      float e  = __expf(dtv * a[s]);
      float bb = bf2f(s < 8 ? (unsigned short)b0[s] : (unsigned short)b1[s - 8]);
      h[s] = e * h[s] + cb * bb;
    }
  }
  float* o = PS + (size_t)tid * 32;
  #pragma unroll
  for (int s = 0; s < 16; ++s) { o[s] = __expf(sdt * a[s]); o[16 + s] = h[s]; }
}

__global__ __launch_bounds__(256) void scan_combine(
    const float* __restrict__ PS, float* __restrict__ H0)
{
  int tid = blockIdx.x * 256 + threadIdx.x;       // bd*16 + s
  int bd = tid >> 4, s = tid & 15;
  float h = 0.f;
  for (int c = 0; c < NC; ++c) {
    size_t idx = (size_t)c * 4096 + bd;
    H0[idx * 16 + s] = h;
    h = PS[idx * 32 + s] * h + PS[idx * 32 + 16 + s];
  }
}

__global__ __launch_bounds__(256) void scan_pass3(
    const unsigned short* __restrict__ dt, const unsigned short* __restrict__ xc,
    const unsigned short* __restrict__ BC, const unsigned short* __restrict__ z,
    const float* __restrict__ Aneg, const float* __restrict__ Dp,
    const float* __restrict__ H0, unsigned short* __restrict__ yg)
{
  int tid = blockIdx.x * 256 + threadIdx.x;
  int bd = tid & 4095, c = tid >> 12;
  int b = bd >> 9, d = bd & 511;
  float a[16], h[16];
  #pragma unroll
  for (int s = 0; s < 16; ++s) {
    a[s] = Aneg[d * 16 + s];
    h[s] = H0[(size_t)tid * 16 + s];
  }
  float dpar = Dp[d];
  size_t rbase = (size_t)b * SEQ + (size_t)c * TC;
  unsigned short dnx = dt[rbase * 512 + d], xnx = xc[rbase * 512 + d], znx = z[rbase * 512 + d];
  const us8* pb = (const us8*)(BC + rbase * 32);
  us8 B0n = pb[0], B1n = pb[1], C0n = pb[2], C1n = pb[3];
  for (int t = 0; t < TC; ++t) {
    float dtv = bf2f(dnx), xv = bf2f(xnx), zv = bf2f(znx);
    us8 b0 = B0n, b1 = B1n, cc0 = C0n, cc1 = C1n;
    if (t + 1 < TC) {
      size_t r = rbase + t + 1;
      dnx = dt[r * 512 + d]; xnx = xc[r * 512 + d]; znx = z[r * 512 + d];
      const us8* p2 = (const us8*)(BC + r * 32);
      B0n = p2[0]; B1n = p2[1]; C0n = p2[2]; C1n = p2[3];
    }
    float cb = dtv * xv, y = 0.f;
    #pragma unroll
    for (int s = 0; s < 16; ++s) {
      float e  = __expf(dtv * a[s]);
      float bb = bf2f(s < 8 ? (unsigned short)b0[s] : (unsigned short)b1[s - 8]);
      float cv = bf2f(s < 8 ? (unsigned short)cc0[s] : (unsigned short)cc1[s - 8]);
      h[s] = e * h[s] + cb * bb;
      y += h[s] * cv;
    }
    float yo = y + dpar * xv;
    float sz = zv / (1.f + __expf(-zv));
    yg[(rbase + t) * 512 + d] = f2bf(yo * sz);
  }
}

// ---------------- LN of m_out -> m_norm (bf16), 4 rows/block ----------------
__global__ __launch_bounds__(256) void ln_kernel(
    const unsigned short* __restrict__ mo, const float* __restrict__ w,
    const float* __restrict__ bb, unsigned short* __restrict__ mn)
{
  int r = blockIdx.x * 4 + (threadIdx.x >> 6);
  int lane = threadIdx.x & 63;
  us4 mv = *(const us4*)(mo + (size_t)r * 256 + lane * 4);
  float v[4];
  #pragma unroll
  for (int j = 0; j < 4; ++j) v[j] = bf2f(mv[j]);
  float s1 = v[0] + v[1] + v[2] + v[3];
  float s2 = v[0]*v[0] + v[1]*v[1] + v[2]*v[2] + v[3]*v[3];
  s1 = wred(s1); s2 = wred(s2);
  float mean = s1 * (1.f / 256.f);
  float var  = s2 * (1.f / 256.f) - mean * mean;
  float rstd = rsqrtf(var + 1e-5f);
  #pragma unroll
  for (int j = 0; j < 4; ++j) {
    int col = lane * 4 + j;
    mn[(size_t)r * 256 + col] = f2bf((v[j] - mean) * rstd * w[col] + bb[col]);
  }
}

extern "C" void kernel_launch(void* const* d_in, const int* in_sizes, int n_in,
                              void* d_out, int out_size, void* d_ws, size_t ws_size,
                              hipStream_t stream) {
  (void)in_sizes; (void)n_in; (void)out_size; (void)ws_size;
  const float* x         = (const float*)d_in[0];
  const float* pos_w     = (const float*)d_in[1];
  const float* pos_b     = (const float*)d_in[2];
  const float* ln_in_w   = (const float*)d_in[3];
  const float* ln_in_b   = (const float*)d_in[4];
  const float* rms_w     = (const float*)d_in[5];
  const float* in_proj_w = (const float*)d_in[6];
  const float* conv_w    = (const float*)d_in[7];
  const float* conv_b    = (const float*)d_in[8];
  const float* x_proj_w  = (const float*)d_in[9];
  const float* dt_proj_w = (const float*)d_in[10];
  const float* dt_proj_b = (const float*)d_in[11];
  const float* A_log     = (const float*)d_in[12];
  const float* D_param   = (const float*)d_in[13];
  const float* out_proj_w= (const float*)d_in[14];
  const float* ln_fwd_w  = (const float*)d_in[15];
  const float* ln_fwd_b  = (const float*)d_in[16];
  const float* proj_w    = (const float*)d_in[17];
  const float* proj_b    = (const float*)d_in[18];
  float* out = (float*)d_out;

  char* w = (char*)d_ws;
  unsigned short* u_buf  = (unsigned short*)(w + 0);
  float*          PS     = (float*)(w + 0);
  unsigned short* mout   = (unsigned short*)(w + 0);
  unsigned short* xsilu  = (unsigned short*)(w + 16777216);
  unsigned short* xm     = (unsigned short*)(w + 33554432);   // then yg
  unsigned short* yg     = xm;
  unsigned short* zb     = (unsigned short*)(w + 67108864);
  unsigned short* xc     = (unsigned short*)(w + 100663296);
  unsigned short* dtb    = (unsigned short*)(w + 134217728);  // then mnorm
  unsigned short* mnorm  = dtb;
  unsigned short* BC     = (unsigned short*)(w + 167772160);
  float*          H0     = (float*)(w + 169869312);
  unsigned short* wInT   = (unsigned short*)(w + 178257920);
  unsigned short* w2T    = (unsigned short*)(w + 178782208);
  unsigned short* woutT  = (unsigned short*)(w + 179437568);
  unsigned short* wprojT = (unsigned short*)(w + 179699712);
  float*          Aneg   = (float*)(w + 179961856);

  prep_kernel<<<3360, 256, 0, stream>>>(in_proj_w, x_proj_w, dt_proj_w, out_proj_w,
                                        proj_w, A_log, wInT, w2T, woutT, wprojT, Aneg);
  pre_kernel<<<8192, 256, 0, stream>>>(x, pos_w, pos_b, ln_in_w, ln_in_b, rms_w, u_buf, xsilu);
  gemm_inproj<<<dim3(8, 256), 256, 0, stream>>>(u_buf, wInT, 256, 256, xm, zb);
  conv_kernel<<<8192, 256, 0, stream>>>(xm, conv_w, conv_b, xc);
  gemm_dtbc<<<dim3(5, 256), 256, 0, stream>>>(xc, w2T, 512, 512, dtb, BC, dt_proj_b);
  scan_pass1<<<512, 256, 0, stream>>>(dtb, xc, BC, Aneg, PS);
  scan_combine<<<256, 256, 0, stream>>>(PS, H0);
  scan_pass3<<<512, 256, 0, stream>>>(dtb, xc, BC, zb, Aneg, D_param, H0, yg);
  gemm_outproj<<<dim3(2, 256), 256, 0, stream>>>(yg, woutT, 512, 512, mout);
  ln_kernel<<<8192, 256, 0, stream>>>(mout, ln_fwd_w, ln_fwd_b, mnorm);
  gemm_final<<<dim3(2, 256), 256, 0, stream>>>(mnorm, xsilu, wprojT, 512, 256, 256,
                                               proj_b, x, out);
}

// Round 5
// 405.526 us; speedup vs baseline: 1.2026x; 1.1924x over previous
//
#include <hip/hip_runtime.h>
#include <stdint.h>

#define SEQ   4096
#define NROWS 32768
#define NC    32
#define TC    128

typedef __attribute__((ext_vector_type(8))) __bf16 bf16x8;
typedef __attribute__((ext_vector_type(4))) float  f32x4;
typedef __attribute__((ext_vector_type(8))) unsigned short us8;
typedef __attribute__((ext_vector_type(4))) unsigned short us4;

__device__ __forceinline__ float bf2f(unsigned short u){
  union { unsigned int i; float f; } c; c.i = ((unsigned int)u) << 16; return c.f;
}
__device__ __forceinline__ unsigned short f2bf(float f){
  union { float f; unsigned int i; } c; c.f = f;
  unsigned int x = c.i;
  x += 0x7fffu + ((x >> 16) & 1u);
  return (unsigned short)(x >> 16);
}
__device__ __forceinline__ float wred(float v){
  #pragma unroll
  for (int m = 32; m > 0; m >>= 1) v += __shfl_xor(v, m, 64);
  return v;
}
__device__ __forceinline__ float softplusf(float x){
  return x > 20.f ? x : log1pf(__expf(x));
}
__device__ __forceinline__ void gload_lds16(const unsigned short* g, unsigned short* l){
  __builtin_amdgcn_global_load_lds((const __attribute__((address_space(1))) void*)g,
                                   (__attribute__((address_space(3))) void*)l, 16, 0, 0);
}

// ---------------- prep: transpose/convert weights, combine dt path ----------------
__global__ __launch_bounds__(256) void prep_kernel(
    const float* __restrict__ in_proj_w, const float* __restrict__ x_proj_w,
    const float* __restrict__ dt_proj_w, const float* __restrict__ out_proj_w,
    const float* __restrict__ proj_w,    const float* __restrict__ A_log,
    unsigned short* __restrict__ wInT, unsigned short* __restrict__ w2T,
    unsigned short* __restrict__ woutT, unsigned short* __restrict__ wprojT,
    float* __restrict__ Aneg)
{
  int i = blockIdx.x * 256 + threadIdx.x;
  if (i < 262144) {                      // in_proj^T : [1024][256]
    int n = i >> 8, k = i & 255;
    wInT[i] = f2bf(in_proj_w[k * 1024 + n]);
    return;
  }
  i -= 262144;
  if (i < 327680) {                      // W2^T : [640][512]  (dt_full | B | C | pad)
    int n = i >> 9, k = i & 511;
    float v = 0.f;
    if (n < 512) {
      #pragma unroll
      for (int r = 0; r < 16; ++r) v += x_proj_w[k * 48 + r] * dt_proj_w[r * 512 + n];
    } else if (n < 544) {
      v = x_proj_w[k * 48 + 16 + (n - 512)];
    }
    w2T[i] = f2bf(v);
    return;
  }
  i -= 327680;
  if (i < 131072) {                      // out_proj^T : [256][512]
    int n = i >> 9, k = i & 511;
    woutT[i] = f2bf(out_proj_w[k * 256 + n]);
    return;
  }
  i -= 131072;
  if (i < 131072) {                      // proj^T : [256][512]
    int n = i >> 9, k = i & 511;
    wprojT[i] = f2bf(proj_w[k * 256 + n]);
    return;
  }
  i -= 131072;
  if (i < 8192) Aneg[i] = -__expf(A_log[i]);   // A = -exp(A_log)
}

// ---------------- fused: pos-encode + LN + silu + rmsnorm (4 rows/block) ----------------
__global__ __launch_bounds__(256) void pre_kernel(
    const float* __restrict__ x, const float* __restrict__ pos_w, const float* __restrict__ pos_b,
    const float* __restrict__ lnw, const float* __restrict__ lnb, const float* __restrict__ rmsw,
    unsigned short* __restrict__ u, unsigned short* __restrict__ xsilu)
{
  int r = blockIdx.x * 4 + (threadIdx.x >> 6);
  int lane = threadIdx.x & 63;
  int t = r & (SEQ - 1);
  float ft = (float)t;
  float denom = (float)(SEQ / 12 + 1);
  float c0  = ft / (float)SEQ;
  float c12 = floorf(ft / 12.f) / denom;
  float c34 = fmodf(ft, 12.f) / 12.f;
  float c56 = floorf((ft + 6.f) / 12.f) / denom;
  float c78 = fmodf(ft + 6.f, 12.f) / 12.f;
  float coords[9] = {c0, c12, c12, c34, c34, c56, c56, c78, c78};

  float4 xv = *(const float4*)(x + (size_t)r * 256 + lane * 4);
  float xin[4] = {xv.x, xv.y, xv.z, xv.w};
  float pe[4];
  #pragma unroll
  for (int j = 0; j < 4; ++j) {
    int col = lane * 4 + j;
    float p = pos_b[col];
    #pragma unroll
    for (int k = 0; k < 9; ++k) p += coords[k] * pos_w[k * 256 + col];
    pe[j] = xin[j] + p;
  }
  float s1 = pe[0] + pe[1] + pe[2] + pe[3];
  float s2 = pe[0]*pe[0] + pe[1]*pe[1] + pe[2]*pe[2] + pe[3]*pe[3];
  s1 = wred(s1); s2 = wred(s2);
  float mean = s1 * (1.f / 256.f);
  float var  = s2 * (1.f / 256.f) - mean * mean;
  float rstd = rsqrtf(var + 1e-5f);
  float xl[4]; float q = 0.f;
  #pragma unroll
  for (int j = 0; j < 4; ++j) {
    int col = lane * 4 + j;
    xl[j] = (pe[j] - mean) * rstd * lnw[col] + lnb[col];
    q += xl[j] * xl[j];
  }
  q = wred(q);
  float rrms = rsqrtf(q * (1.f / 256.f) + 1e-5f);
  #pragma unroll
  for (int j = 0; j < 4; ++j) {
    int col = lane * 4 + j;
    u[(size_t)r * 256 + col] = f2bf(xl[j] * rrms * rmsw[col]);
    float v = xl[j];
    xsilu[(size_t)r * 256 + col] = f2bf(v / (1.f + __expf(-v)));
  }
}

// ---------------- depthwise conv(4) + silu ----------------
__global__ __launch_bounds__(256) void conv_kernel(
    const unsigned short* __restrict__ xm, const float* __restrict__ cw,
    const float* __restrict__ cb, unsigned short* __restrict__ xc)
{
  int tid = blockIdx.x * 256 + threadIdx.x;      // 8*4096*64
  int d8 = (tid & 63) * 8;
  int t  = (tid >> 6) & (SEQ - 1);
  int b  = tid >> 18;
  float acc[8];
  #pragma unroll
  for (int j = 0; j < 8; ++j) acc[j] = cb[d8 + j];
  #pragma unroll
  for (int k = 0; k < 4; ++k) {
    int ts = t - 3 + k;
    if (ts >= 0) {
      us8 v = *(const us8*)(xm + ((size_t)b * SEQ + ts) * 512 + d8);
      #pragma unroll
      for (int j = 0; j < 8; ++j) acc[j] += bf2f(v[j]) * cw[k * 512 + d8 + j];
    }
  }
  us8 o;
  #pragma unroll
  for (int j = 0; j < 8; ++j) {
    float s = acc[j] / (1.f + __expf(-acc[j]));
    o[j] = f2bf(s);
  }
  *(us8*)(xc + ((size_t)b * SEQ + t) * 512 + d8) = o;
}

// ================= barrier-free skinny GEMM =================
// C[M][N] = A[M][K] @ Bt[N][K]^T.  Whole B-tile [BN][K] resident in LDS
// (loaded once, one barrier).  Each of 8 waves owns 32 rows; A-fragments
// stream global->VGPR (exact mfma A-frag layout: lane=(row l&15, k=(l>>4)*8)),
// 4-step-deep prefetch, NO barriers in the K-loop.
// LDS B swizzle: slot kblk_lds = kblk_g ^ (col&7)  (8 16B-slots -> conflict-free).
// Read addr decomposes as  base(lane) + j*16*K + ((s^cb)<<5)  [verified algebra].
// MODE 0: split store xm|z   1: softplus->dt | BC   2: bf16   3: fp32 +bias +x
template<int KSTEPS, int MODE, bool ASPLIT>
__global__ __launch_bounds__(512) void sgemm(
    const unsigned short* __restrict__ A0, const unsigned short* __restrict__ A1,
    const unsigned short* __restrict__ Bt,
    unsigned short* __restrict__ O0, unsigned short* __restrict__ O1,
    const float* __restrict__ e0, const float* __restrict__ e1,
    float* __restrict__ fout)
{
  constexpr int K  = KSTEPS * 32;
  constexpr int BN = (K == 512) ? 64 : 128;     // LDS = BN*K*2 = 64 KiB
  constexpr int NT = BN / 16;
  constexpr int KB = K / 8;                     // 16B blocks per col
  __shared__ unsigned short Bs[BN * K];

  const int tid = threadIdx.x, wave = tid >> 6, lane = tid & 63;
  const int bcol = blockIdx.x * BN;
  const int brow = blockIdx.y * 256 + wave * 32;
  const int r = lane & 15, sub = lane >> 4;

  // ---- stage whole B tile: linear LDS dest, inverse-swizzled global source ----
  #pragma unroll
  for (int i = 0; i < 8; ++i) {
    int gi  = wave * 8 + i;
    int blk = gi * 64 + lane;                   // 16B-block linear index
    int col = blk / KB, kb = blk % KB;
    gload_lds16(Bt + (size_t)(bcol + col) * K + ((kb ^ (col & 7)) * 8),
                Bs + gi * 512);
  }
  __syncthreads();                              // the only barrier

  constexpr int astride = ASPLIT ? 256 : K;
  const unsigned short* Ab0 = A0 + (size_t)(brow + r) * astride + sub * 8;
  const unsigned short* Ab1 = ASPLIT ? (A1 + (size_t)(brow + r) * 256 + sub * 8)
                                     : (const unsigned short*)nullptr;

  const int bbase = r * K + ((sub ^ (r & 3)) * 8);   // lane-const part of B addr
  const int cbs   = ((r >> 2) & 1) << 5;             // step-XOR bit

  f32x4 acc0[NT], acc1[NT];
  #pragma unroll
  for (int j = 0; j < NT; ++j) { acc0[j] = f32x4{0.f,0.f,0.f,0.f}; acc1[j] = f32x4{0.f,0.f,0.f,0.f}; }

  bf16x8 ab0[4], ab1[4];
  #pragma unroll
  for (int p = 0; p < 4; ++p) {                 // prologue: 4-deep prefetch
    const unsigned short* ap = (!ASPLIT || p < 8) ? Ab0 : Ab1;
    int kk = (ASPLIT && p >= 8) ? (p - 8) * 32 : p * 32;
    ab0[p & 3] = *(const bf16x8*)(ap + kk);
    ab1[p & 3] = *(const bf16x8*)(ap + 16 * astride + kk);
  }

  #pragma unroll
  for (int s = 0; s < KSTEPS; ++s) {
    const int so = (s << 5) ^ cbs;              // == ((s^cb)<<5)
    bf16x8 bv[NT];
    #pragma unroll
    for (int j = 0; j < NT; ++j)
      bv[j] = *(const bf16x8*)(Bs + bbase + j * (16 * K) + so);
    bf16x8 av0 = ab0[s & 3], av1 = ab1[s & 3];
    #pragma unroll
    for (int j = 0; j < NT; ++j) {
      acc0[j] = __builtin_amdgcn_mfma_f32_16x16x32_bf16(av0, bv[j], acc0[j], 0, 0, 0);
      acc1[j] = __builtin_amdgcn_mfma_f32_16x16x32_bf16(av1, bv[j], acc1[j], 0, 0, 0);
    }
    if (s + 4 < KSTEPS) {                       // refill ring slot
      int p = s + 4;
      const unsigned short* ap = (!ASPLIT || p < 8) ? Ab0 : Ab1;
      int kk = (ASPLIT && p >= 8) ? (p - 8) * 32 : p * 32;
      ab0[p & 3] = *(const bf16x8*)(ap + kk);
      ab1[p & 3] = *(const bf16x8*)(ap + 16 * astride + kk);
    }
  }

  // ---- epilogue: C row=(lane>>4)*4+rr, col=lane&15 per 16x16 tile ----
  #pragma unroll
  for (int t = 0; t < 2; ++t) {
    #pragma unroll
    for (int j = 0; j < NT; ++j) {
      int col = bcol + j * 16 + r;
      f32x4 v4 = t ? acc1[j] : acc0[j];
      #pragma unroll
      for (int rr = 0; rr < 4; ++rr) {
        int row = brow + t * 16 + sub * 4 + rr;
        float v = v4[rr];
        if (MODE == 0) {
          if (col < 512) O0[(size_t)row * 512 + col] = f2bf(v);
          else           O1[(size_t)row * 512 + (col - 512)] = f2bf(v);
        } else if (MODE == 1) {
          if (col < 512)      O0[(size_t)row * 512 + col] = f2bf(softplusf(v + e0[col]));
          else if (col < 544) O1[(size_t)row * 32 + (col - 512)] = f2bf(v);
        } else if (MODE == 2) {
          O0[(size_t)row * 256 + col] = f2bf(v);
        } else {
          fout[(size_t)row * 256 + col] = v + e0[col] + e1[(size_t)row * 256 + col];
        }
      }
    }
  }
}

// ---------------- chunked selective scan ----------------
__global__ __launch_bounds__(256) void scan_pass1(
    const unsigned short* __restrict__ dt, const unsigned short* __restrict__ xc,
    const unsigned short* __restrict__ BC, const float* __restrict__ Aneg,
    float* __restrict__ PS)
{
  int tid = blockIdx.x * 256 + threadIdx.x;       // c*4096 + bd
  int bd = tid & 4095, c = tid >> 12;
  int b = bd >> 9, d = bd & 511;
  float a[16], h[16];
  #pragma unroll
  for (int s = 0; s < 16; ++s) { a[s] = Aneg[d * 16 + s]; h[s] = 0.f; }
  size_t rbase = (size_t)b * SEQ + (size_t)c * TC;
  float sdt = 0.f;
  unsigned short dnx = dt[rbase * 512 + d], xnx = xc[rbase * 512 + d];
  const us8* pb = (const us8*)(BC + rbase * 32);
  us8 B0n = pb[0], B1n = pb[1];
  for (int t = 0; t < TC; ++t) {
    float dtv = bf2f(dnx), xv = bf2f(xnx);
    us8 b0 = B0n, b1 = B1n;
    if (t + 1 < TC) {
      size_t rr = rbase + t + 1;
      dnx = dt[rr * 512 + d]; xnx = xc[rr * 512 + d];
      const us8* p2 = (const us8*)(BC + rr * 32);
      B0n = p2[0]; B1n = p2[1];
    }
    sdt += dtv;
    float cbv = dtv * xv;
    #pragma unroll
    for (int s = 0; s < 16; ++s) {
      float e  = __expf(dtv * a[s]);
      float bb = bf2f(s < 8 ? (unsigned short)b0[s] : (unsigned short)b1[s - 8]);
      h[s] = e * h[s] + cbv * bb;
    }
  }
  float* o = PS + (size_t)tid * 32;
  #pragma unroll
  for (int s = 0; s < 16; ++s) { o[s] = __expf(sdt * a[s]); o[16 + s] = h[s]; }
}

__global__ __launch_bounds__(256) void scan_combine(
    const float* __restrict__ PS, float* __restrict__ H0)
{
  int tid = blockIdx.x * 256 + threadIdx.x;       // bd*16 + s
  int bd = tid >> 4, s = tid & 15;
  float h = 0.f;
  for (int c = 0; c < NC; ++c) {
    size_t idx = (size_t)c * 4096 + bd;
    H0[idx * 16 + s] = h;
    h = PS[idx * 32 + s] * h + PS[idx * 32 + 16 + s];
  }
}

__global__ __launch_bounds__(256) void scan_pass3(
    const unsigned short* __restrict__ dt, const unsigned short* __restrict__ xc,
    const unsigned short* __restrict__ BC, const unsigned short* __restrict__ z,
    const float* __restrict__ Aneg, const float* __restrict__ Dp,
    const float* __restrict__ H0, unsigned short* __restrict__ yg)
{
  int tid = blockIdx.x * 256 + threadIdx.x;
  int bd = tid & 4095, c = tid >> 12;
  int b = bd >> 9, d = bd & 511;
  float a[16], h[16];
  #pragma unroll
  for (int s = 0; s < 16; ++s) {
    a[s] = Aneg[d * 16 + s];
    h[s] = H0[(size_t)tid * 16 + s];
  }
  float dpar = Dp[d];
  size_t rbase = (size_t)b * SEQ + (size_t)c * TC;
  unsigned short dnx = dt[rbase * 512 + d], xnx = xc[rbase * 512 + d], znx = z[rbase * 512 + d];
  const us8* pb = (const us8*)(BC + rbase * 32);
  us8 B0n = pb[0], B1n = pb[1], C0n = pb[2], C1n = pb[3];
  for (int t = 0; t < TC; ++t) {
    float dtv = bf2f(dnx), xv = bf2f(xnx), zv = bf2f(znx);
    us8 b0 = B0n, b1 = B1n, cc0 = C0n, cc1 = C1n;
    if (t + 1 < TC) {
      size_t rr = rbase + t + 1;
      dnx = dt[rr * 512 + d]; xnx = xc[rr * 512 + d]; znx = z[rr * 512 + d];
      const us8* p2 = (const us8*)(BC + rr * 32);
      B0n = p2[0]; B1n = p2[1]; C0n = p2[2]; C1n = p2[3];
    }
    float cbv = dtv * xv, y = 0.f;
    #pragma unroll
    for (int s = 0; s < 16; ++s) {
      float e  = __expf(dtv * a[s]);
      float bb = bf2f(s < 8 ? (unsigned short)b0[s] : (unsigned short)b1[s - 8]);
      float cv = bf2f(s < 8 ? (unsigned short)cc0[s] : (unsigned short)cc1[s - 8]);
      h[s] = e * h[s] + cbv * bb;
      y += h[s] * cv;
    }
    float yo = y + dpar * xv;
    float sz = zv / (1.f + __expf(-zv));
    yg[(rbase + t) * 512 + d] = f2bf(yo * sz);
  }
}

// ---------------- LN of m_out -> m_norm (bf16), 4 rows/block ----------------
__global__ __launch_bounds__(256) void ln_kernel(
    const unsigned short* __restrict__ mo, const float* __restrict__ w,
    const float* __restrict__ bb, unsigned short* __restrict__ mn)
{
  int r = blockIdx.x * 4 + (threadIdx.x >> 6);
  int lane = threadIdx.x & 63;
  us4 mv = *(const us4*)(mo + (size_t)r * 256 + lane * 4);
  float v[4];
  #pragma unroll
  for (int j = 0; j < 4; ++j) v[j] = bf2f(mv[j]);
  float s1 = v[0] + v[1] + v[2] + v[3];
  float s2 = v[0]*v[0] + v[1]*v[1] + v[2]*v[2] + v[3]*v[3];
  s1 = wred(s1); s2 = wred(s2);
  float mean = s1 * (1.f / 256.f);
  float var  = s2 * (1.f / 256.f) - mean * mean;
  float rstd = rsqrtf(var + 1e-5f);
  #pragma unroll
  for (int j = 0; j < 4; ++j) {
    int col = lane * 4 + j;
    mn[(size_t)r * 256 + col] = f2bf((v[j] - mean) * rstd * w[col] + bb[col]);
  }
}

extern "C" void kernel_launch(void* const* d_in, const int* in_sizes, int n_in,
                              void* d_out, int out_size, void* d_ws, size_t ws_size,
                              hipStream_t stream) {
  (void)in_sizes; (void)n_in; (void)out_size; (void)ws_size;
  const float* x         = (const float*)d_in[0];
  const float* pos_w     = (const float*)d_in[1];
  const float* pos_b     = (const float*)d_in[2];
  const float* ln_in_w   = (const float*)d_in[3];
  const float* ln_in_b   = (const float*)d_in[4];
  const float* rms_w     = (const float*)d_in[5];
  const float* in_proj_w = (const float*)d_in[6];
  const float* conv_w    = (const float*)d_in[7];
  const float* conv_b    = (const float*)d_in[8];
  const float* x_proj_w  = (const float*)d_in[9];
  const float* dt_proj_w = (const float*)d_in[10];
  const float* dt_proj_b = (const float*)d_in[11];
  const float* A_log     = (const float*)d_in[12];
  const float* D_param   = (const float*)d_in[13];
  const float* out_proj_w= (const float*)d_in[14];
  const float* ln_fwd_w  = (const float*)d_in[15];
  const float* ln_fwd_b  = (const float*)d_in[16];
  const float* proj_w    = (const float*)d_in[17];
  const float* proj_b    = (const float*)d_in[18];
  float* out = (float*)d_out;

  char* w = (char*)d_ws;
  unsigned short* u_buf  = (unsigned short*)(w + 0);
  float*          PS     = (float*)(w + 0);
  unsigned short* mout   = (unsigned short*)(w + 0);
  unsigned short* xsilu  = (unsigned short*)(w + 16777216);
  unsigned short* xm     = (unsigned short*)(w + 33554432);   // then yg
  unsigned short* yg     = xm;
  unsigned short* zb     = (unsigned short*)(w + 67108864);
  unsigned short* xc     = (unsigned short*)(w + 100663296);
  unsigned short* dtb    = (unsigned short*)(w + 134217728);  // then mnorm
  unsigned short* mnorm  = dtb;
  unsigned short* BC     = (unsigned short*)(w + 167772160);
  float*          H0     = (float*)(w + 169869312);
  unsigned short* wInT   = (unsigned short*)(w + 178257920);
  unsigned short* w2T    = (unsigned short*)(w + 178782208);
  unsigned short* woutT  = (unsigned short*)(w + 179437568);
  unsigned short* wprojT = (unsigned short*)(w + 179699712);
  float*          Aneg   = (float*)(w + 179961856);

  prep_kernel<<<3360, 256, 0, stream>>>(in_proj_w, x_proj_w, dt_proj_w, out_proj_w,
                                        proj_w, A_log, wInT, w2T, woutT, wprojT, Aneg);
  pre_kernel<<<8192, 256, 0, stream>>>(x, pos_w, pos_b, ln_in_w, ln_in_b, rms_w, u_buf, xsilu);
  // in_proj: M=32768 N=1024 K=256, BN=128 -> grid 8x128
  sgemm<8, 0, false><<<dim3(8, 128), 512, 0, stream>>>(
      u_buf, nullptr, wInT, xm, zb, nullptr, nullptr, nullptr);
  conv_kernel<<<8192, 256, 0, stream>>>(xm, conv_w, conv_b, xc);
  // dt/B/C: M=32768 N=576(eff) K=512, BN=64 -> grid 9x128
  sgemm<16, 1, false><<<dim3(9, 128), 512, 0, stream>>>(
      xc, nullptr, w2T, dtb, BC, dt_proj_b, nullptr, nullptr);
  scan_pass1<<<512, 256, 0, stream>>>(dtb, xc, BC, Aneg, PS);
  scan_combine<<<256, 256, 0, stream>>>(PS, H0);
  scan_pass3<<<512, 256, 0, stream>>>(dtb, xc, BC, zb, Aneg, D_param, H0, yg);
  // out_proj: M=32768 N=256 K=512, BN=64 -> grid 4x128
  sgemm<16, 2, false><<<dim3(4, 128), 512, 0, stream>>>(
      yg, nullptr, woutT, mout, nullptr, nullptr, nullptr, nullptr);
  ln_kernel<<<8192, 256, 0, stream>>>(mout, ln_fwd_w, ln_fwd_b, mnorm);
  // final: M=32768 N=256 K=512 (A split mnorm|xsilu), BN=64 -> grid 4x128
  sgemm<16, 3, true><<<dim3(4, 128), 512, 0, stream>>>(
      mnorm, xsilu, wprojT, nullptr, nullptr, proj_b, x, out);
}

// Round 6
// 386.290 us; speedup vs baseline: 1.2625x; 1.0498x over previous
//
#include <hip/hip_runtime.h>
#include <stdint.h>

#define SEQ   4096
#define NROWS 32768
#define NC    32
#define TC    128

typedef __attribute__((ext_vector_type(8))) __bf16 bf16x8;
typedef __attribute__((ext_vector_type(4))) float  f32x4;
typedef __attribute__((ext_vector_type(8))) unsigned short us8;
typedef __attribute__((ext_vector_type(4))) unsigned short us4;

__device__ __forceinline__ float bf2f(unsigned short u){
  union { unsigned int i; float f; } c; c.i = ((unsigned int)u) << 16; return c.f;
}
__device__ __forceinline__ unsigned short f2bf(float f){
  union { float f; unsigned int i; } c; c.f = f;
  unsigned int x = c.i;
  x += 0x7fffu + ((x >> 16) & 1u);
  return (unsigned short)(x >> 16);
}
__device__ __forceinline__ unsigned int pack2(float a, float b){
  return (unsigned int)f2bf(a) | ((unsigned int)f2bf(b) << 16);
}
__device__ __forceinline__ float wred(float v){
  #pragma unroll
  for (int m = 32; m > 0; m >>= 1) v += __shfl_xor(v, m, 64);
  return v;
}
__device__ __forceinline__ float softplusf(float x){
  return x > 20.f ? x : log1pf(__expf(x));
}
__device__ __forceinline__ void gload_lds16(const unsigned short* g, unsigned short* l){
  __builtin_amdgcn_global_load_lds((const __attribute__((address_space(1))) void*)g,
                                   (__attribute__((address_space(3))) void*)l, 16, 0, 0);
}

// ---------------- prep: transpose/convert weights, combine dt path ----------------
__global__ __launch_bounds__(256) void prep_kernel(
    const float* __restrict__ in_proj_w, const float* __restrict__ x_proj_w,
    const float* __restrict__ dt_proj_w, const float* __restrict__ out_proj_w,
    const float* __restrict__ proj_w,    const float* __restrict__ A_log,
    unsigned short* __restrict__ wInT, unsigned short* __restrict__ w2T,
    unsigned short* __restrict__ woutT, unsigned short* __restrict__ wprojT,
    float* __restrict__ Aneg)
{
  int i = blockIdx.x * 256 + threadIdx.x;
  if (i < 262144) {                      // in_proj^T : [1024][256]
    int n = i >> 8, k = i & 255;
    wInT[i] = f2bf(in_proj_w[k * 1024 + n]);
    return;
  }
  i -= 262144;
  if (i < 327680) {                      // W2^T : [640][512]  (dt_full | B | C | pad)
    int n = i >> 9, k = i & 511;
    float v = 0.f;
    if (n < 512) {
      #pragma unroll
      for (int r = 0; r < 16; ++r) v += x_proj_w[k * 48 + r] * dt_proj_w[r * 512 + n];
    } else if (n < 544) {
      v = x_proj_w[k * 48 + 16 + (n - 512)];
    }
    w2T[i] = f2bf(v);
    return;
  }
  i -= 327680;
  if (i < 131072) {                      // out_proj^T : [256][512]
    int n = i >> 9, k = i & 511;
    woutT[i] = f2bf(out_proj_w[k * 256 + n]);
    return;
  }
  i -= 131072;
  if (i < 131072) {                      // proj^T : [256][512]
    int n = i >> 9, k = i & 511;
    wprojT[i] = f2bf(proj_w[k * 256 + n]);
    return;
  }
  i -= 131072;
  if (i < 8192) Aneg[i] = -__expf(A_log[i]);   // A = -exp(A_log)
}

// ---------------- fused: pos-encode + LN + silu + rmsnorm (4 rows/block) ----------------
__global__ __launch_bounds__(256) void pre_kernel(
    const float* __restrict__ x, const float* __restrict__ pos_w, const float* __restrict__ pos_b,
    const float* __restrict__ lnw, const float* __restrict__ lnb, const float* __restrict__ rmsw,
    unsigned short* __restrict__ u, unsigned short* __restrict__ xsilu)
{
  int r = blockIdx.x * 4 + (threadIdx.x >> 6);
  int lane = threadIdx.x & 63;
  int t = r & (SEQ - 1);
  float ft = (float)t;
  float denom = (float)(SEQ / 12 + 1);
  float c0  = ft / (float)SEQ;
  float c12 = floorf(ft / 12.f) / denom;
  float c34 = fmodf(ft, 12.f) / 12.f;
  float c56 = floorf((ft + 6.f) / 12.f) / denom;
  float c78 = fmodf(ft + 6.f, 12.f) / 12.f;
  float coords[9] = {c0, c12, c12, c34, c34, c56, c56, c78, c78};

  float4 xv = *(const float4*)(x + (size_t)r * 256 + lane * 4);
  float xin[4] = {xv.x, xv.y, xv.z, xv.w};
  float pe[4];
  #pragma unroll
  for (int j = 0; j < 4; ++j) {
    int col = lane * 4 + j;
    float p = pos_b[col];
    #pragma unroll
    for (int k = 0; k < 9; ++k) p += coords[k] * pos_w[k * 256 + col];
    pe[j] = xin[j] + p;
  }
  float s1 = pe[0] + pe[1] + pe[2] + pe[3];
  float s2 = pe[0]*pe[0] + pe[1]*pe[1] + pe[2]*pe[2] + pe[3]*pe[3];
  s1 = wred(s1); s2 = wred(s2);
  float mean = s1 * (1.f / 256.f);
  float var  = s2 * (1.f / 256.f) - mean * mean;
  float rstd = rsqrtf(var + 1e-5f);
  float xl[4]; float q = 0.f;
  #pragma unroll
  for (int j = 0; j < 4; ++j) {
    int col = lane * 4 + j;
    xl[j] = (pe[j] - mean) * rstd * lnw[col] + lnb[col];
    q += xl[j] * xl[j];
  }
  q = wred(q);
  float rrms = rsqrtf(q * (1.f / 256.f) + 1e-5f);
  #pragma unroll
  for (int j = 0; j < 4; ++j) {
    int col = lane * 4 + j;
    u[(size_t)r * 256 + col] = f2bf(xl[j] * rrms * rmsw[col]);
    float v = xl[j];
    xsilu[(size_t)r * 256 + col] = f2bf(v / (1.f + __expf(-v)));
  }
}

// ---------------- depthwise conv(4) + silu ----------------
__global__ __launch_bounds__(256) void conv_kernel(
    const unsigned short* __restrict__ xm, const float* __restrict__ cw,
    const float* __restrict__ cb, unsigned short* __restrict__ xc)
{
  int tid = blockIdx.x * 256 + threadIdx.x;      // 8*4096*64
  int d8 = (tid & 63) * 8;
  int t  = (tid >> 6) & (SEQ - 1);
  int b  = tid >> 18;
  float acc[8];
  #pragma unroll
  for (int j = 0; j < 8; ++j) acc[j] = cb[d8 + j];
  #pragma unroll
  for (int k = 0; k < 4; ++k) {
    int ts = t - 3 + k;
    if (ts >= 0) {
      us8 v = *(const us8*)(xm + ((size_t)b * SEQ + ts) * 512 + d8);
      #pragma unroll
      for (int j = 0; j < 8; ++j) acc[j] += bf2f(v[j]) * cw[k * 512 + d8 + j];
    }
  }
  us8 o;
  #pragma unroll
  for (int j = 0; j < 8; ++j) {
    float s = acc[j] / (1.f + __expf(-acc[j]));
    o[j] = f2bf(s);
  }
  *(us8*)(xc + ((size_t)b * SEQ + t) * 512 + d8) = o;
}

// ================= barrier-free skinny GEMM =================
// C[M][N] = A[M][K] @ Bt[N][K]^T.  Whole B-tile [BN][K] in LDS (one barrier).
// 8 waves x 32 rows; A streams global->VGPR (exact mfma frag layout), 4-deep ring,
// NO barriers in K-loop.  B LDS swizzle: blk_lds = blk_g ^ (col&7), conflict-free.
// OPERAND SWAP: acc = mfma(bv, av, acc) computes C^T per-tile so each lane holds
// 4 CONSECUTIVE OUTPUT COLS of one row -> packed 8B (or float4) stores.
// XCD remap: all col-blocks of one A row-panel land on the same XCD (L2 reuse).
// MODE 0: split xm|z   1: softplus->dt | BC   2: bf16   3: fp32 +bias +x
template<int KSTEPS, int MODE, bool ASPLIT>
__global__ __launch_bounds__(512) void sgemm(
    const unsigned short* __restrict__ A0, const unsigned short* __restrict__ A1,
    const unsigned short* __restrict__ Bt,
    unsigned short* __restrict__ O0, unsigned short* __restrict__ O1,
    const float* __restrict__ e0, const float* __restrict__ e1,
    float* __restrict__ fout)
{
  constexpr int K  = KSTEPS * 32;
  constexpr int BN = (K == 512) ? 64 : 128;     // LDS = BN*K*2 = 64 KiB
  constexpr int NT = BN / 16;
  constexpr int KB = K / 8;                     // 16B blocks per col
  __shared__ unsigned short Bs[BN * K];

  const int tid = threadIdx.x, wave = tid >> 6, lane = tid & 63;
  // XCD remap: logical (bx,by) with by%8 == hw_id%8 -> A panel stays in one L2
  const int id  = blockIdx.y * gridDim.x + blockIdx.x;
  const int gx  = gridDim.x;
  const int pos = id >> 3;
  const int bx  = pos % gx;
  const int by  = (pos / gx) * 8 + (id & 7);
  const int bcol = bx * BN;
  const int brow = by * 256 + wave * 32;
  const int r = lane & 15, sub = lane >> 4;

  // ---- stage whole B tile: linear LDS dest, inverse-swizzled global source ----
  #pragma unroll
  for (int i = 0; i < 8; ++i) {
    int gi  = wave * 8 + i;
    int blk = gi * 64 + lane;                   // 16B-block linear index
    int col = blk / KB, kb = blk % KB;
    gload_lds16(Bt + (size_t)(bcol + col) * K + ((kb ^ (col & 7)) * 8),
                Bs + gi * 512);
  }
  __syncthreads();                              // the only barrier

  constexpr int astride = ASPLIT ? 256 : K;
  const unsigned short* Ab0 = A0 + (size_t)(brow + r) * astride + sub * 8;
  const unsigned short* Ab1 = ASPLIT ? (A1 + (size_t)(brow + r) * 256 + sub * 8)
                                     : (const unsigned short*)nullptr;

  const int bbase = r * K + ((sub ^ (r & 3)) * 8);   // lane-const part of B addr
  const int cbs   = ((r >> 2) & 1) << 5;             // block-bit-2 of the XOR

  f32x4 acc0[NT], acc1[NT];
  #pragma unroll
  for (int j = 0; j < NT; ++j) { acc0[j] = f32x4{0.f,0.f,0.f,0.f}; acc1[j] = f32x4{0.f,0.f,0.f,0.f}; }

  bf16x8 ab0[4], ab1[4];
  #pragma unroll
  for (int p = 0; p < 4; ++p) {                 // prologue: 4-deep prefetch
    const unsigned short* ap = (!ASPLIT || p < 8) ? Ab0 : Ab1;
    int kk = (ASPLIT && p >= 8) ? (p - 8) * 32 : p * 32;
    ab0[p & 3] = *(const bf16x8*)(ap + kk);
    ab1[p & 3] = *(const bf16x8*)(ap + 16 * astride + kk);
  }

  #pragma unroll
  for (int s = 0; s < KSTEPS; ++s) {
    const int so = (s << 5) ^ cbs;              // == ((s*4+sub)^(r&7) slot walk
    bf16x8 bv[NT];
    #pragma unroll
    for (int j = 0; j < NT; ++j)
      bv[j] = *(const bf16x8*)(Bs + bbase + j * (16 * K) + so);
    bf16x8 av0 = ab0[s & 3], av1 = ab1[s & 3];
    #pragma unroll
    for (int j = 0; j < NT; ++j) {              // swapped operands -> C^T tiles
      acc0[j] = __builtin_amdgcn_mfma_f32_16x16x32_bf16(bv[j], av0, acc0[j], 0, 0, 0);
      acc1[j] = __builtin_amdgcn_mfma_f32_16x16x32_bf16(bv[j], av1, acc1[j], 0, 0, 0);
    }
    if (s + 4 < KSTEPS) {                       // refill ring slot
      int p = s + 4;
      const unsigned short* ap = (!ASPLIT || p < 8) ? Ab0 : Ab1;
      int kk = (ASPLIT && p >= 8) ? (p - 8) * 32 : p * 32;
      ab0[p & 3] = *(const bf16x8*)(ap + kk);
      ab1[p & 3] = *(const bf16x8*)(ap + 16 * astride + kk);
    }
  }

  // ---- epilogue: lane holds row = brow+t*16+r, cols = bcol+j*16+sub*4+[0..3] ----
  #pragma unroll
  for (int t = 0; t < 2; ++t) {
    const int row = brow + t * 16 + r;
    #pragma unroll
    for (int j = 0; j < NT; ++j) {
      f32x4 v4 = t ? acc1[j] : acc0[j];
      const int colb = bcol + j * 16 + sub * 4;
      if (MODE == 0) {
        uint2 pp = {pack2(v4[0], v4[1]), pack2(v4[2], v4[3])};
        if (colb < 512) *(uint2*)(O0 + (size_t)row * 512 + colb) = pp;
        else            *(uint2*)(O1 + (size_t)row * 512 + (colb - 512)) = pp;
      } else if (MODE == 1) {
        if (colb < 512) {
          float s0 = softplusf(v4[0] + e0[colb]),     s1 = softplusf(v4[1] + e0[colb + 1]);
          float s2 = softplusf(v4[2] + e0[colb + 2]), s3 = softplusf(v4[3] + e0[colb + 3]);
          uint2 pp = {pack2(s0, s1), pack2(s2, s3)};
          *(uint2*)(O0 + (size_t)row * 512 + colb) = pp;
        } else if (colb < 544) {
          uint2 pp = {pack2(v4[0], v4[1]), pack2(v4[2], v4[3])};
          *(uint2*)(O1 + (size_t)row * 32 + (colb - 512)) = pp;
        }
      } else if (MODE == 2) {
        uint2 pp = {pack2(v4[0], v4[1]), pack2(v4[2], v4[3])};
        *(uint2*)(O0 + (size_t)row * 256 + colb) = pp;
      } else {
        float4 b4 = *(const float4*)(e0 + colb);
        float4 x4 = *(const float4*)(e1 + (size_t)row * 256 + colb);
        float4 o4 = {v4[0] + b4.x + x4.x, v4[1] + b4.y + x4.y,
                     v4[2] + b4.z + x4.z, v4[3] + b4.w + x4.w};
        *(float4*)(fout + (size_t)row * 256 + colb) = o4;
      }
    }
  }
}

// ---------------- chunked selective scan ----------------
__global__ __launch_bounds__(256) void scan_pass1(
    const unsigned short* __restrict__ dt, const unsigned short* __restrict__ xc,
    const unsigned short* __restrict__ BC, const float* __restrict__ Aneg,
    float* __restrict__ PS)
{
  int tid = blockIdx.x * 256 + threadIdx.x;       // c*4096 + bd
  int bd = tid & 4095, c = tid >> 12;
  int b = bd >> 9, d = bd & 511;
  float a[16], h[16];
  #pragma unroll
  for (int s = 0; s < 16; ++s) { a[s] = Aneg[d * 16 + s]; h[s] = 0.f; }
  size_t rbase = (size_t)b * SEQ + (size_t)c * TC;
  float sdt = 0.f;
  unsigned short dnx = dt[rbase * 512 + d], xnx = xc[rbase * 512 + d];
  const us8* pb = (const us8*)(BC + rbase * 32);
  us8 B0n = pb[0], B1n = pb[1];
  for (int t = 0; t < TC; ++t) {
    float dtv = bf2f(dnx), xv = bf2f(xnx);
    us8 b0 = B0n, b1 = B1n;
    if (t + 1 < TC) {
      size_t rr = rbase + t + 1;
      dnx = dt[rr * 512 + d]; xnx = xc[rr * 512 + d];
      const us8* p2 = (const us8*)(BC + rr * 32);
      B0n = p2[0]; B1n = p2[1];
    }
    sdt += dtv;
    float cbv = dtv * xv;
    #pragma unroll
    for (int s = 0; s < 16; ++s) {
      float e  = __expf(dtv * a[s]);
      float bb = bf2f(s < 8 ? (unsigned short)b0[s] : (unsigned short)b1[s - 8]);
      h[s] = e * h[s] + cbv * bb;
    }
  }
  float* o = PS + (size_t)tid * 32;
  #pragma unroll
  for (int s = 0; s < 16; ++s) { o[s] = __expf(sdt * a[s]); o[16 + s] = h[s]; }
}

__global__ __launch_bounds__(256) void scan_combine(
    const float* __restrict__ PS, float* __restrict__ H0)
{
  int tid = blockIdx.x * 256 + threadIdx.x;       // bd*16 + s
  int bd = tid >> 4, s = tid & 15;
  float h = 0.f;
  for (int c = 0; c < NC; ++c) {
    size_t idx = (size_t)c * 4096 + bd;
    H0[idx * 16 + s] = h;
    h = PS[idx * 32 + s] * h + PS[idx * 32 + 16 + s];
  }
}

__global__ __launch_bounds__(256) void scan_pass3(
    const unsigned short* __restrict__ dt, const unsigned short* __restrict__ xc,
    const unsigned short* __restrict__ BC, const unsigned short* __restrict__ z,
    const float* __restrict__ Aneg, const float* __restrict__ Dp,
    const float* __restrict__ H0, unsigned short* __restrict__ yg)
{
  int tid = blockIdx.x * 256 + threadIdx.x;
  int bd = tid & 4095, c = tid >> 12;
  int b = bd >> 9, d = bd & 511;
  float a[16], h[16];
  #pragma unroll
  for (int s = 0; s < 16; ++s) {
    a[s] = Aneg[d * 16 + s];
    h[s] = H0[(size_t)tid * 16 + s];
  }
  float dpar = Dp[d];
  size_t rbase = (size_t)b * SEQ + (size_t)c * TC;
  unsigned short dnx = dt[rbase * 512 + d], xnx = xc[rbase * 512 + d], znx = z[rbase * 512 + d];
  const us8* pb = (const us8*)(BC + rbase * 32);
  us8 B0n = pb[0], B1n = pb[1], C0n = pb[2], C1n = pb[3];
  for (int t = 0; t < TC; ++t) {
    float dtv = bf2f(dnx), xv = bf2f(xnx), zv = bf2f(znx);
    us8 b0 = B0n, b1 = B1n, cc0 = C0n, cc1 = C1n;
    if (t + 1 < TC) {
      size_t rr = rbase + t + 1;
      dnx = dt[rr * 512 + d]; xnx = xc[rr * 512 + d]; znx = z[rr * 512 + d];
      const us8* p2 = (const us8*)(BC + rr * 32);
      B0n = p2[0]; B1n = p2[1]; C0n = p2[2]; C1n = p2[3];
    }
    float cbv = dtv * xv, y = 0.f;
    #pragma unroll
    for (int s = 0; s < 16; ++s) {
      float e  = __expf(dtv * a[s]);
      float bb = bf2f(s < 8 ? (unsigned short)b0[s] : (unsigned short)b1[s - 8]);
      float cv = bf2f(s < 8 ? (unsigned short)cc0[s] : (unsigned short)cc1[s - 8]);
      h[s] = e * h[s] + cbv * bb;
      y += h[s] * cv;
    }
    float yo = y + dpar * xv;
    float sz = zv / (1.f + __expf(-zv));
    yg[(rbase + t) * 512 + d] = f2bf(yo * sz);
  }
}

// ---------------- LN of m_out -> m_norm (bf16), 4 rows/block ----------------
__global__ __launch_bounds__(256) void ln_kernel(
    const unsigned short* __restrict__ mo, const float* __restrict__ w,
    const float* __restrict__ bb, unsigned short* __restrict__ mn)
{
  int r = blockIdx.x * 4 + (threadIdx.x >> 6);
  int lane = threadIdx.x & 63;
  us4 mv = *(const us4*)(mo + (size_t)r * 256 + lane * 4);
  float v[4];
  #pragma unroll
  for (int j = 0; j < 4; ++j) v[j] = bf2f(mv[j]);
  float s1 = v[0] + v[1] + v[2] + v[3];
  float s2 = v[0]*v[0] + v[1]*v[1] + v[2]*v[2] + v[3]*v[3];
  s1 = wred(s1); s2 = wred(s2);
  float mean = s1 * (1.f / 256.f);
  float var  = s2 * (1.f / 256.f) - mean * mean;
  float rstd = rsqrtf(var + 1e-5f);
  #pragma unroll
  for (int j = 0; j < 4; ++j) {
    int col = lane * 4 + j;
    mn[(size_t)r * 256 + col] = f2bf((v[j] - mean) * rstd * w[col] + bb[col]);
  }
}

extern "C" void kernel_launch(void* const* d_in, const int* in_sizes, int n_in,
                              void* d_out, int out_size, void* d_ws, size_t ws_size,
                              hipStream_t stream) {
  (void)in_sizes; (void)n_in; (void)out_size; (void)ws_size;
  const float* x         = (const float*)d_in[0];
  const float* pos_w     = (const float*)d_in[1];
  const float* pos_b     = (const float*)d_in[2];
  const float* ln_in_w   = (const float*)d_in[3];
  const float* ln_in_b   = (const float*)d_in[4];
  const float* rms_w     = (const float*)d_in[5];
  const float* in_proj_w = (const float*)d_in[6];
  const float* conv_w    = (const float*)d_in[7];
  const float* conv_b    = (const float*)d_in[8];
  const float* x_proj_w  = (const float*)d_in[9];
  const float* dt_proj_w = (const float*)d_in[10];
  const float* dt_proj_b = (const float*)d_in[11];
  const float* A_log     = (const float*)d_in[12];
  const float* D_param   = (const float*)d_in[13];
  const float* out_proj_w= (const float*)d_in[14];
  const float* ln_fwd_w  = (const float*)d_in[15];
  const float* ln_fwd_b  = (const float*)d_in[16];
  const float* proj_w    = (const float*)d_in[17];
  const float* proj_b    = (const float*)d_in[18];
  float* out = (float*)d_out;

  char* w = (char*)d_ws;
  unsigned short* u_buf  = (unsigned short*)(w + 0);
  float*          PS     = (float*)(w + 0);
  unsigned short* mout   = (unsigned short*)(w + 0);
  unsigned short* xsilu  = (unsigned short*)(w + 16777216);
  unsigned short* xm     = (unsigned short*)(w + 33554432);   // then yg
  unsigned short* yg     = xm;
  unsigned short* zb     = (unsigned short*)(w + 67108864);
  unsigned short* xc     = (unsigned short*)(w + 100663296);
  unsigned short* dtb    = (unsigned short*)(w + 134217728);  // then mnorm
  unsigned short* mnorm  = dtb;
  unsigned short* BC     = (unsigned short*)(w + 167772160);
  float*          H0     = (float*)(w + 169869312);
  unsigned short* wInT   = (unsigned short*)(w + 178257920);
  unsigned short* w2T    = (unsigned short*)(w + 178782208);
  unsigned short* woutT  = (unsigned short*)(w + 179437568);
  unsigned short* wprojT = (unsigned short*)(w + 179699712);
  float*          Aneg   = (float*)(w + 179961856);

  prep_kernel<<<3360, 256, 0, stream>>>(in_proj_w, x_proj_w, dt_proj_w, out_proj_w,
                                        proj_w, A_log, wInT, w2T, woutT, wprojT, Aneg);
  pre_kernel<<<8192, 256, 0, stream>>>(x, pos_w, pos_b, ln_in_w, ln_in_b, rms_w, u_buf, xsilu);
  // in_proj: M=32768 N=1024 K=256, BN=128 -> grid 8x128
  sgemm<8, 0, false><<<dim3(8, 128), 512, 0, stream>>>(
      u_buf, nullptr, wInT, xm, zb, nullptr, nullptr, nullptr);
  conv_kernel<<<8192, 256, 0, stream>>>(xm, conv_w, conv_b, xc);
  // dt/B/C: M=32768 N=576(eff) K=512, BN=64 -> grid 9x128
  sgemm<16, 1, false><<<dim3(9, 128), 512, 0, stream>>>(
      xc, nullptr, w2T, dtb, BC, dt_proj_b, nullptr, nullptr);
  scan_pass1<<<512, 256, 0, stream>>>(dtb, xc, BC, Aneg, PS);
  scan_combine<<<256, 256, 0, stream>>>(PS, H0);
  scan_pass3<<<512, 256, 0, stream>>>(dtb, xc, BC, zb, Aneg, D_param, H0, yg);
  // out_proj: M=32768 N=256 K=512, BN=64 -> grid 4x128
  sgemm<16, 2, false><<<dim3(4, 128), 512, 0, stream>>>(
      yg, nullptr, woutT, mout, nullptr, nullptr, nullptr, nullptr);
  ln_kernel<<<8192, 256, 0, stream>>>(mout, ln_fwd_w, ln_fwd_b, mnorm);
  // final: M=32768 N=256 K=512 (A split mnorm|xsilu), BN=64 -> grid 4x128
  sgemm<16, 3, true><<<dim3(4, 128), 512, 0, stream>>>(
      mnorm, xsilu, wprojT, nullptr, nullptr, proj_b, x, out);
}